// Round 2
// baseline (1275.446 us; speedup 1.0000x reference)
//
#include <hip/hip_runtime.h>
#include <math.h>

#define CDIM 128
#define EDIM 512
#define BLK 256
#define MT 64                 // vectors per block
#define NVEC 262144           // 8*32*32*32
#define SPATIAL 32768
#define QELEMS 33554432LL
#define TIE_T 4e-6f

typedef __bf16 bf16x8 __attribute__((ext_vector_type(8)));
typedef float  f32x4  __attribute__((ext_vector_type(4)));

struct WS {
  float  wnh[EDIM];                 // 0.5*||e||^2
  int    counts[EDIM];
  double lossAcc;
  double _pad;                      // align wph to 16B
  unsigned short wph[EDIM * CDIM];  // w hi bf16, MFMA-fragment order
  unsigned short wpl[EDIM * CDIM];  // w lo bf16, MFMA-fragment order
};

__device__ inline unsigned short bfbits(float f) {
  union { __bf16 b; unsigned short u; } cv; cv.b = (__bf16)f; return cv.u;
}
// split x into bf16 hi (RNE) + bf16 lo (RNE of residual); pack pairs
__device__ inline void split2(float x0, float x1, unsigned& hv, unsigned& lv) {
  unsigned short h0 = bfbits(x0), h1 = bfbits(x1);
  float r0 = x0 - __uint_as_float((unsigned)h0 << 16);
  float r1 = x1 - __uint_as_float((unsigned)h1 << 16);
  unsigned short l0 = bfbits(r0), l1 = bfbits(r1);
  hv = (unsigned)h0 | ((unsigned)h1 << 16);
  lv = (unsigned)l0 | ((unsigned)l1 << 16);
}

__device__ inline void ins3(float v, int ix, float& m1, float& m2, float& m3,
                            int& j1, int& j2) {
  bool q1 = (v < m1) || (v == m1 && ix < j1);
  bool q2 = (v < m2) || (v == m2 && ix < j2);
  if (q1)      { m3 = m2; m2 = m1; j2 = j1; m1 = v; j1 = ix; }
  else if (q2) { m3 = m2; m2 = v; j2 = ix; }
  else if (v < m3) { m3 = v; }
}

// ---- pre-pass (64 blocks x 256 thr): half norms, zero accumulators, bf16 split of w
// wph fragment order: for e,k: etile=e>>4,row=e&15,kt=k>>5,g=(k>>3)&3,j=k&7:
//   idx = ((etile*4+kt)*64 + g*16 + row)*8 + j   -> lane-linear, coalesced 16B loads
__global__ __launch_bounds__(256) void vq_pre(const float* __restrict__ wt,
                                              WS* __restrict__ ws, int buildWP) {
  const int tid = threadIdx.x, bid = blockIdx.x;
  const int e = bid * 8 + (tid >> 5);
  const int k0 = (tid & 31) * 4;
  float4 F = *(const float4*)(wt + (size_t)e * CDIM + k0);
  float nrm = F.x * F.x + F.y * F.y + F.z * F.z + F.w * F.w;
#pragma unroll
  for (int off = 1; off < 32; off <<= 1) nrm += __shfl_xor(nrm, off);
  if ((tid & 31) == 0) ws->wnh[e] = 0.5f * nrm;
  if (tid < 8) ws->counts[bid * 8 + tid] = 0;
  if (bid == 0 && tid == 0) ws->lossAcc = 0.0;
  if (buildWP) {
    const int etile = e >> 4, row = e & 15;
    const int kt = k0 >> 5, g = (k0 >> 3) & 3, j0 = k0 & 7;    // j0 in {0,4}
    size_t idx = ((size_t)(etile * 4 + kt) * 64 + g * 16 + row) * 8 + j0;
    unsigned hv0, lv0, hv1, lv1;
    split2(F.x, F.y, hv0, lv0);
    split2(F.z, F.w, hv1, lv1);
    *(uint2*)&ws->wph[idx] = make_uint2(hv0, hv1);
    *(uint2*)&ws->wpl[idx] = make_uint2(lv0, lv1);
  }
}

__device__ double score64(const float* __restrict__ in, const float* __restrict__ wt,
                          size_t xoff, int e) {
  const float* w = wt + (size_t)e * CDIM;
  double a = 0.0;
  for (int c = 0; c < CDIM; ++c) {
    double wd = (double)w[c];
    double xv = (double)in[xoff + (size_t)c * SPATIAL];
    a = fma(wd, fma(0.5, wd, -xv), a);    // 0.5||e||^2 - x.e, exact ordering
  }
  return a;
}

// x LDS layout (per hi/lo array, ushort):
//   elem(m,k) = (k>>3)*512 + (m>>4)*128 + swz(m&15)*8 + (k&7),  swz(v)=v^(v>>2)
// B-fragment (lane: m=l&15, kslice g=l>>4) = one aligned ds_read_b128; swz keeps both
// stride-4-m staging writes and stride-1-m reads at the per-quarter bank minimum.
template <bool USEWP>
__global__ __launch_bounds__(BLK, 4) void vq_main(const float* __restrict__ in,
                                                  const float* __restrict__ wt,
                                                  WS* __restrict__ ws,
                                                  float* __restrict__ out_q,
                                                  float* __restrict__ enc) {
  __shared__ __align__(16) unsigned short xhi[8192];   // 16384 B
  __shared__ __align__(16) unsigned short xlo[8192];   // 16384 B
  __shared__ float cb1[MT][5], cb2[MT][5], cb3[MT][5]; // cross-wave merge (pad 5)
  __shared__ int   ci1[MT][5], ci2[MT][5];
  __shared__ int    sIdx[MT];
  __shared__ double lredw[4];

  const int tid = threadIdx.x;
  const int n0 = blockIdx.x * MT;
  const int b  = n0 >> 15;
  const int s0 = n0 & (SPATIAL - 1);
  const size_t ibase = (size_t)b * CDIM * SPATIAL;

  // ---- stage x: 8 c x 4 m per thread, 4x8 reg transpose, b128 LDS writes
  {
    const int mq = tid & 15;            // m0 = 4*mq
    const int cg = tid >> 4;            // c-group of 8: 0..15
    const int m0 = mq * 4, c0 = cg * 8;
    float4 F[8];
#pragma unroll
    for (int i = 0; i < 8; ++i)
      F[i] = *(const float4*)(in + ibase + (size_t)(c0 + i) * SPATIAL + s0 + m0);
#pragma unroll
    for (int mi = 0; mi < 4; ++mi) {
      const int m = m0 + mi;
      unsigned hv[4], lv[4];
#pragma unroll
      for (int p = 0; p < 4; ++p)
        split2(((const float*)&F[2 * p])[mi], ((const float*)&F[2 * p + 1])[mi],
               hv[p], lv[p]);
      const int fm = (m & 15) ^ ((m & 15) >> 2);
      const int elem = cg * 512 + (m >> 4) * 128 + fm * 8;
      *(uint4*)&xhi[elem] = make_uint4(hv[0], hv[1], hv[2], hv[3]);
      *(uint4*)&xlo[elem] = make_uint4(lv[0], lv[1], lv[2], lv[3]);
    }
  }
  __syncthreads();

  const int lane = tid & 63, wv = tid >> 6;
  const int col = lane & 15, g = lane >> 4;
  const int fcol = col ^ (col >> 2);

  float b1[4], b2[4], b3[4]; int i1[4], i2[4];
#pragma unroll
  for (int i = 0; i < 4; ++i) { b1[i] = 1e30f; b2[i] = 1e30f; b3[i] = 1e30f; i1[i] = 0; i2[i] = 0; }

  // ---- main loop: NO barriers (w fragments come from global, L1/L2-resident)
  for (int ch = 0; ch < 8; ++ch) {
    const int etile = ch * 4 + wv;      // this wave's 16-row e-tile
    bf16x8 ah[4], al[4];
    if (USEWP) {
#pragma unroll
      for (int kt = 0; kt < 4; ++kt) {
        size_t aoff = ((size_t)(etile * 4 + kt) * 64 + lane) * 8;
        ah[kt] = *(const bf16x8*)&ws->wph[aoff];
        al[kt] = *(const bf16x8*)&ws->wpl[aoff];
      }
    } else {
      const int e = etile * 16 + col;
#pragma unroll
      for (int kt = 0; kt < 4; ++kt) {
        const float* wp = wt + (size_t)e * CDIM + kt * 32 + g * 8;
        float4 Fa = *(const float4*)wp, Fb = *(const float4*)(wp + 4);
        float xf[8] = {Fa.x, Fa.y, Fa.z, Fa.w, Fb.x, Fb.y, Fb.z, Fb.w};
        bf16x8 h, l;
#pragma unroll
        for (int j = 0; j < 8; ++j) {
          __bf16 hb = (__bf16)xf[j];
          float r = xf[j] - (float)hb;
          h[j] = hb; l[j] = (__bf16)r;
        }
        ah[kt] = h; al[kt] = l;
      }
    }

    f32x4 acc[4];
#pragma unroll
    for (int mt = 0; mt < 4; ++mt) {
      f32x4 a = {0.f, 0.f, 0.f, 0.f};
#pragma unroll
      for (int kt = 0; kt < 4; ++kt) {
        const int xb = (kt * 4 + g) * 512 + mt * 128 + fcol * 8;
        bf16x8 bh = *(const bf16x8*)&xhi[xb];
        bf16x8 bl = *(const bf16x8*)&xlo[xb];
        a = __builtin_amdgcn_mfma_f32_16x16x32_bf16(ah[kt], bh, a, 0, 0, 0);
        a = __builtin_amdgcn_mfma_f32_16x16x32_bf16(ah[kt], bl, a, 0, 0, 0);
        a = __builtin_amdgcn_mfma_f32_16x16x32_bf16(al[kt], bh, a, 0, 0, 0);
        // lo*lo term <= 128*|x_lo||w_lo| ~ 5e-9: dropped
      }
      acc[mt] = a;
    }

    // epilogue: scores + per-lane top-3 (e ascending -> first-index ties)
    const int e0 = ch * 64 + wv * 16 + g * 4;
    const float4 wn = *(const float4*)&ws->wnh[e0];
#pragma unroll
    for (int mt = 0; mt < 4; ++mt) {
#pragma unroll
      for (int r = 0; r < 4; ++r) {
        float sc = ((const float*)&wn)[r] - acc[mt][r];
        ins3(sc, e0 + r, b1[mt], b2[mt], b3[mt], i1[mt], i2[mt]);
      }
    }
  }

  // ---- intra-wave butterfly merge over g (disjoint e-sets each round)
#pragma unroll
  for (int mt = 0; mt < 4; ++mt) {
#pragma unroll
    for (int sh = 0; sh < 2; ++sh) {
      const int off = 16 << sh;
      float p1 = __shfl_xor(b1[mt], off), p2 = __shfl_xor(b2[mt], off),
            p3 = __shfl_xor(b3[mt], off);
      int q1 = __shfl_xor(i1[mt], off), q2 = __shfl_xor(i2[mt], off);
      ins3(p1, q1, b1[mt], b2[mt], b3[mt], i1[mt], i2[mt]);
      ins3(p2, q2, b1[mt], b2[mt], b3[mt], i1[mt], i2[mt]);
      ins3(p3, 0x7fffffff, b1[mt], b2[mt], b3[mt], i1[mt], i2[mt]);
    }
  }
  if (g == 0) {
#pragma unroll
    for (int mt = 0; mt < 4; ++mt) {
      const int m = mt * 16 + col;
      cb1[m][wv] = b1[mt]; cb2[m][wv] = b2[mt]; cb3[m][wv] = b3[mt];
      ci1[m][wv] = i1[mt]; ci2[m][wv] = i2[mt];
    }
  }
  __syncthreads();

  if (tid < MT) {
    const int vec = tid;
    float m1 = cb1[vec][0], m2 = cb2[vec][0], m3 = cb3[vec][0];
    int j1 = ci1[vec][0], j2 = ci2[vec][0];
#pragma unroll
    for (int t = 1; t < 4; ++t) {
      ins3(cb1[vec][t], ci1[vec][t], m1, m2, m3, j1, j2);
      ins3(cb2[vec][t], ci2[vec][t], m1, m2, m3, j1, j2);
      ins3(cb3[vec][t], 0x7fffffff, m1, m2, m3, j1, j2);
    }
    int bi = j1;
    const size_t xoff = ibase + s0 + vec;
    if (m3 - m1 < TIE_T) {
      // 3-way near-tie: full exact scan (vanishingly rare)
      double bd = 1e300; int bj = 0;
      for (int e = 0; e < EDIM; ++e) {
        double a = score64(in, wt, xoff, e);
        if (a < bd) { bd = a; bj = e; }
      }
      bi = bj;
    } else if (m2 - m1 < TIE_T) {
      double s1 = score64(in, wt, xoff, j1);
      double s2 = score64(in, wt, xoff, j2);
      if (s2 < s1 || (s2 == s1 && j2 < j1)) bi = j2;
    }
    sIdx[vec] = bi;
    atomicAdd(&ws->counts[bi], 1);
  }
  __syncthreads();

  // ---- out_q + loss: x reconstructed from LDS hi/lo (no global re-read)
  {
    const int vec = tid & (MT - 1);
    const int qd  = tid >> 6;             // 4 quarters of 32 channels
    const int bi  = sIdx[vec];
    const float* wq = wt + (size_t)bi * CDIM;
    const size_t gbase = ibase + s0 + vec;
    const int fv = (vec & 15) ^ ((vec & 15) >> 2);
    double ls = 0.0;
#pragma unroll
    for (int cc = 0; cc < 32; cc += 4) {
      const int c = qd * 32 + cc;
      const int elem = (c >> 3) * 512 + (vec >> 4) * 128 + fv * 8 + (c & 7);
      uint2 hq = *(const uint2*)&xhi[elem];
      uint2 lq = *(const uint2*)&xlo[elem];
      float xs0 = __uint_as_float(hq.x << 16)        + __uint_as_float(lq.x << 16);
      float xs1 = __uint_as_float(hq.x & 0xffff0000u) + __uint_as_float(lq.x & 0xffff0000u);
      float xs2 = __uint_as_float(hq.y << 16)        + __uint_as_float(lq.y << 16);
      float xs3 = __uint_as_float(hq.y & 0xffff0000u) + __uint_as_float(lq.y & 0xffff0000u);
      float4 qv = *(const float4*)(wq + c);
      __builtin_nontemporal_store(qv.x, out_q + gbase + (size_t)(c + 0) * SPATIAL);
      __builtin_nontemporal_store(qv.y, out_q + gbase + (size_t)(c + 1) * SPATIAL);
      __builtin_nontemporal_store(qv.z, out_q + gbase + (size_t)(c + 2) * SPATIAL);
      __builtin_nontemporal_store(qv.w, out_q + gbase + (size_t)(c + 3) * SPATIAL);
      double d0 = (double)qv.x - (double)xs0; ls = fma(d0, d0, ls);
      double d1 = (double)qv.y - (double)xs1; ls = fma(d1, d1, ls);
      double d2 = (double)qv.z - (double)xs2; ls = fma(d2, d2, ls);
      double d3 = (double)qv.w - (double)xs3; ls = fma(d3, d3, ls);
    }
#pragma unroll
    for (int off = 32; off > 0; off >>= 1) ls += __shfl_down(ls, off);
    if (lane == 0) lredw[wv] = ls;
  }
  __syncthreads();
  if (tid == 0) atomicAdd(&ws->lossAcc, lredw[0] + lredw[1] + lredw[2] + lredw[3]);

  // ---- encodings: 64 one-hot rows, 256 u64 columns
  {
    const size_t r0 = (size_t)blockIdx.x * MT;
    const int c0 = tid * 2;
    unsigned long long* e2 = (unsigned long long*)enc;
    for (int r = 0; r < MT; ++r) {
      int idx = sIdx[r];
      union { float2 f; unsigned long long u; } cvt;
      cvt.f.x = (idx == c0) ? 1.0f : 0.0f;
      cvt.f.y = (idx == c0 + 1) ? 1.0f : 0.0f;
      __builtin_nontemporal_store(cvt.u, e2 + (r0 + (size_t)r) * (EDIM / 2) + tid);
    }
  }
}

// ---- finalize
__global__ __launch_bounds__(512) void vq_fin(const WS* __restrict__ ws, float* __restrict__ out) {
  __shared__ double red[EDIM];
  int t = threadIdx.x;
  double p = (double)ws->counts[t] * (1.0 / (double)NVEC);
  red[t] = p * log(p + 1e-10);
  __syncthreads();
  for (int off = 256; off > 0; off >>= 1) {
    if (t < off) red[t] += red[t + off];
    __syncthreads();
  }
  if (t == 0) {
    out[0] = (float)(1.25 * ws->lossAcc / (double)QELEMS);
    out[1 + QELEMS] = (float)exp(-red[0]);
  }
}

extern "C" void kernel_launch(void* const* d_in, const int* in_sizes, int n_in,
                              void* d_out, int out_size, void* d_ws, size_t ws_size,
                              hipStream_t stream) {
  const float* in = (const float*)d_in[0];
  const float* wt = (const float*)d_in[1];
  float* out = (float*)d_out;
  WS* ws = (WS*)d_ws;

  float* out_q = out + 1;
  float* enc   = out + 2 + QELEMS;

  const bool useWP = (ws_size >= sizeof(WS));
  vq_pre<<<dim3(64), dim3(256), 0, stream>>>(wt, ws, useWP ? 1 : 0);
  if (useWP)
    vq_main<true><<<dim3(NVEC / MT), dim3(BLK), 0, stream>>>(in, wt, ws, out_q, enc);
  else
    vq_main<false><<<dim3(NVEC / MT), dim3(BLK), 0, stream>>>(in, wt, ws, out_q, enc);
  vq_fin<<<dim3(1), dim3(512), 0, stream>>>(ws, out);
}

// Round 4
// 1057.593 us; speedup vs baseline: 1.2060x; 1.2060x over previous
//
#include <hip/hip_runtime.h>
#include <math.h>

#define CDIM 128
#define EDIM 512
#define BLK 256
#define MT 64                 // vectors per block
#define ECH 64                // embeddings per staged chunk
#define NCH (EDIM / ECH)      // 8 chunks
#define WROW 136              // padded LDS row stride (ushorts) for w tiles
#define NVEC 262144           // 8*32*32*32
#define SPATIAL 32768
#define QELEMS 33554432LL
#define TIE_T 4e-6f

typedef __bf16 bf16x8 __attribute__((ext_vector_type(8)));
typedef float  f32x4  __attribute__((ext_vector_type(4)));

struct WS {
  float  wnh[EDIM];                 // 0.5*||e||^2
  int    counts[EDIM];
  double lossAcc;
  double _pad;                      // align wph to 16B
  unsigned short wph[EDIM * CDIM];  // w hi bf16, row-major [e][k]
  unsigned short wpl[EDIM * CDIM];  // w lo bf16, row-major [e][k]
};

__device__ inline unsigned short bfbits(float f) {
  union { __bf16 b; unsigned short u; } cv; cv.b = (__bf16)f; return cv.u;
}
// split pair into bf16 hi (RNE) + bf16 lo (RNE of residual); pack
__device__ inline void split2(float x0, float x1, unsigned& hv, unsigned& lv) {
  unsigned short h0 = bfbits(x0), h1 = bfbits(x1);
  float r0 = x0 - __uint_as_float((unsigned)h0 << 16);
  float r1 = x1 - __uint_as_float((unsigned)h1 << 16);
  unsigned short l0 = bfbits(r0), l1 = bfbits(r1);
  hv = (unsigned)h0 | ((unsigned)h1 << 16);
  lv = (unsigned)l0 | ((unsigned)l1 << 16);
}

__device__ inline void ins3(float v, int ix, float& m1, float& m2, float& m3,
                            int& j1, int& j2) {
  bool q1 = (v < m1) || (v == m1 && ix < j1);
  bool q2 = (v < m2) || (v == m2 && ix < j2);
  if (q1)      { m3 = m2; m2 = m1; j2 = j1; m1 = v; j1 = ix; }
  else if (q2) { m3 = m2; m2 = v; j2 = ix; }
  else if (v < m3) { m3 = v; }
}

// ---- pre-pass (64 blocks x 256 thr): half norms, zero accumulators, bf16 split of w
__global__ __launch_bounds__(256) void vq_pre(const float* __restrict__ wt,
                                              WS* __restrict__ ws, int buildWP) {
  const int tid = threadIdx.x, bid = blockIdx.x;
  const int e = bid * 8 + (tid >> 5);
  const int k0 = (tid & 31) * 4;
  float4 F = *(const float4*)(wt + (size_t)e * CDIM + k0);
  float nrm = F.x * F.x + F.y * F.y + F.z * F.z + F.w * F.w;
#pragma unroll
  for (int off = 1; off < 32; off <<= 1) nrm += __shfl_xor(nrm, off);
  if ((tid & 31) == 0) ws->wnh[e] = 0.5f * nrm;
  if (tid < 8) ws->counts[bid * 8 + tid] = 0;
  if (bid == 0 && tid == 0) ws->lossAcc = 0.0;
  if (buildWP) {
    unsigned hv0, lv0, hv1, lv1;
    split2(F.x, F.y, hv0, lv0);
    split2(F.z, F.w, hv1, lv1);
    *(uint2*)&ws->wph[(size_t)e * CDIM + k0] = make_uint2(hv0, hv1);
    *(uint2*)&ws->wpl[(size_t)e * CDIM + k0] = make_uint2(lv0, lv1);
  }
}

__device__ double score64(const float* __restrict__ in, const float* __restrict__ wt,
                          size_t xoff, int e) {
  const float* w = wt + (size_t)e * CDIM;
  double a = 0.0;
  for (int c = 0; c < CDIM; ++c) {
    double wd = (double)w[c];
    double xv = (double)in[xoff + (size_t)c * SPATIAL];
    a = fma(wd, fma(0.5, wd, -xv), a);    // 0.5||e||^2 - x.e, exact ordering
  }
  return a;
}

// x LDS layout (per hi/lo array, ushort):
//   elem(m,k) = (k>>3)*512 + (m>>4)*128 + swz(m&15)*8 + (k&7),  swz(v)=v^(v>>2)
// w LDS layout: [row][k] with row stride WROW=136 ushorts (272B, 16B-aligned);
//   both b128 staging writes and b128 fragment reads are bank-uniform.
template <bool USEWP>
__global__ __launch_bounds__(BLK, 2) void vq_main(const float* __restrict__ in,
                                                  const float* __restrict__ wt,
                                                  WS* __restrict__ ws,
                                                  float* __restrict__ out_q,
                                                  float* __restrict__ enc) {
  __shared__ __align__(16) unsigned short xhi[8192];       // 16384 B
  __shared__ __align__(16) unsigned short xlo[8192];       // 16384 B
  __shared__ __align__(16) unsigned short wls[2 * ECH * WROW]; // 34816 B (hi, then lo)
  __shared__ int    hist[EDIM];                            // 2048 B
  __shared__ int    sIdx[MT];
  __shared__ double lredw[4];

  const int tid = threadIdx.x;
  const int n0 = blockIdx.x * MT;
  const int b  = n0 >> 15;
  const int s0 = n0 & (SPATIAL - 1);
  const size_t ibase = (size_t)b * CDIM * SPATIAL;

  for (int e = tid; e < EDIM; e += BLK) hist[e] = 0;

  // ---- stage x: 8 c x 4 m per thread, reg transpose, b128 LDS writes
  {
    const int mq = tid & 15;            // m0 = 4*mq
    const int cg = tid >> 4;            // c-group of 8: 0..15
    const int m0 = mq * 4, c0 = cg * 8;
    float4 F[8];
#pragma unroll
    for (int i = 0; i < 8; ++i)
      F[i] = *(const float4*)(in + ibase + (size_t)(c0 + i) * SPATIAL + s0 + m0);
#pragma unroll
    for (int mi = 0; mi < 4; ++mi) {
      const int m = m0 + mi;
      unsigned hv[4], lv[4];
#pragma unroll
      for (int p = 0; p < 4; ++p)
        split2(((const float*)&F[2 * p])[mi], ((const float*)&F[2 * p + 1])[mi],
               hv[p], lv[p]);
      const int fm = (m & 15) ^ ((m & 15) >> 2);
      const int elem = cg * 512 + (m >> 4) * 128 + fm * 8;
      *(uint4*)&xhi[elem] = make_uint4(hv[0], hv[1], hv[2], hv[3]);
      *(uint4*)&xlo[elem] = make_uint4(lv[0], lv[1], lv[2], lv[3]);
    }
  }

  const int lane = tid & 63, wv = tid >> 6;
  const int col = lane & 15, g = lane >> 4;
  const int fcol = col ^ (col >> 2);

  // staging map: thread covers w row se (within chunk), k-quarter skq
  const int se  = tid >> 2;
  const int skq = (tid & 3) * 32;

  float b1[4], b2[4], b3[4]; int i1[4], i2[4];
#pragma unroll
  for (int i = 0; i < 4; ++i) { b1[i] = 1e30f; b2[i] = 1e30f; b3[i] = 1e30f; i1[i] = 0; i2[i] = 0; }

  uint4 Gh[4], Gl[4], Hh[4], Hl[4];
#pragma unroll
  for (int i = 0; i < 4; ++i) {
    Hh[i] = make_uint4(0, 0, 0, 0);
    Hl[i] = make_uint4(0, 0, 0, 0);
  }

  auto loadW = [&](int ch, uint4* Th, uint4* Tl) {
    if (USEWP) {
      const uint4* ph = (const uint4*)&ws->wph[(size_t)(ch * ECH + se) * CDIM + skq];
      const uint4* pl = (const uint4*)&ws->wpl[(size_t)(ch * ECH + se) * CDIM + skq];
#pragma unroll
      for (int i = 0; i < 4; ++i) { Th[i] = ph[i]; Tl[i] = pl[i]; }
    } else {
      const float* wp = wt + (size_t)(ch * ECH + se) * CDIM + skq;
#pragma unroll
      for (int i = 0; i < 4; ++i) {
        float4 A = *(const float4*)(wp + i * 8);
        float4 B = *(const float4*)(wp + i * 8 + 4);
        unsigned hv0, lv0, hv1, lv1, hv2, lv2, hv3, lv3;
        split2(A.x, A.y, hv0, lv0); split2(A.z, A.w, hv1, lv1);
        split2(B.x, B.y, hv2, lv2); split2(B.z, B.w, hv3, lv3);
        Th[i] = make_uint4(hv0, hv1, hv2, hv3);
        Tl[i] = make_uint4(lv0, lv1, lv2, lv3);
      }
    }
  };

  loadW(0, Gh, Gl);

  for (int ch = 0; ch < NCH; ++ch) {
    __syncthreads();                  // w LDS free (covers x staging on ch==0)
#pragma unroll
    for (int i = 0; i < 4; ++i) {
      *(uint4*)&wls[se * WROW + skq + i * 8] = Gh[i];
      *(uint4*)&wls[ECH * WROW + se * WROW + skq + i * 8] = Gl[i];
    }
    if (ch + 1 < NCH) loadW(ch + 1, Hh, Hl);   // T14: issue early, drains next iter
    __syncthreads();

    // ---- A fragments (this wave's 16-row e-tile within the chunk)
    bf16x8 ah[4], al[4];
#pragma unroll
    for (int kt = 0; kt < 4; ++kt) {
      const int rb = (wv * 16 + col) * WROW + kt * 32 + g * 8;
      ah[kt] = *(const bf16x8*)&wls[rb];
      al[kt] = *(const bf16x8*)&wls[ECH * WROW + rb];
    }

    // ---- MFMA: 3-pass bf16 split (lo*lo term ~5e-9: dropped)
    f32x4 acc[4];
#pragma unroll
    for (int mt = 0; mt < 4; ++mt) {
      f32x4 a = {0.f, 0.f, 0.f, 0.f};
#pragma unroll
      for (int kt = 0; kt < 4; ++kt) {
        const int xb = (kt * 4 + g) * 512 + mt * 128 + fcol * 8;
        bf16x8 bh = *(const bf16x8*)&xhi[xb];
        bf16x8 bl = *(const bf16x8*)&xlo[xb];
        a = __builtin_amdgcn_mfma_f32_16x16x32_bf16(ah[kt], bh, a, 0, 0, 0);
        a = __builtin_amdgcn_mfma_f32_16x16x32_bf16(ah[kt], bl, a, 0, 0, 0);
        a = __builtin_amdgcn_mfma_f32_16x16x32_bf16(al[kt], bh, a, 0, 0, 0);
      }
      acc[mt] = a;
    }

    // ---- epilogue: scores + per-lane top-3 (e ascending -> first-index ties)
    const int e0 = ch * ECH + wv * 16 + g * 4;
    const float4 wn = *(const float4*)&ws->wnh[e0];
#pragma unroll
    for (int mt = 0; mt < 4; ++mt) {
#pragma unroll
      for (int r = 0; r < 4; ++r) {
        float sc = ((const float*)&wn)[r] - acc[mt][r];
        ins3(sc, e0 + r, b1[mt], b2[mt], b3[mt], i1[mt], i2[mt]);
      }
    }
#pragma unroll
    for (int i = 0; i < 4; ++i) { Gh[i] = Hh[i]; Gl[i] = Hl[i]; }
  }

  // ---- intra-wave butterfly merge over g (disjoint e-sets each round)
#pragma unroll
  for (int mt = 0; mt < 4; ++mt) {
#pragma unroll
    for (int sh = 0; sh < 2; ++sh) {
      const int off = 16 << sh;
      float p1 = __shfl_xor(b1[mt], off), p2 = __shfl_xor(b2[mt], off),
            p3 = __shfl_xor(b3[mt], off);
      int q1 = __shfl_xor(i1[mt], off), q2 = __shfl_xor(i2[mt], off);
      ins3(p1, q1, b1[mt], b2[mt], b3[mt], i1[mt], i2[mt]);
      ins3(p2, q2, b1[mt], b2[mt], b3[mt], i1[mt], i2[mt]);
      ins3(p3, 0x7fffffff, b1[mt], b2[mt], b3[mt], i1[mt], i2[mt]);
    }
  }

  __syncthreads();   // w tiles dead; overlay merge arrays on wls (x stays live!)
  {
    char* mb = (char*)wls;
    float (*cb1)[5] = (float(*)[5])mb;
    float (*cb2)[5] = (float(*)[5])(mb + 1280);
    float (*cb3)[5] = (float(*)[5])(mb + 2560);
    int   (*ci1)[5] = (int(*)[5])(mb + 3840);
    int   (*ci2)[5] = (int(*)[5])(mb + 5120);

    if (g == 0) {
#pragma unroll
      for (int mt = 0; mt < 4; ++mt) {
        const int m = mt * 16 + col;
        cb1[m][wv] = b1[mt]; cb2[m][wv] = b2[mt]; cb3[m][wv] = b3[mt];
        ci1[m][wv] = i1[mt]; ci2[m][wv] = i2[mt];
      }
    }
    __syncthreads();

    if (tid < MT) {
      const int vec = tid;
      float m1 = cb1[vec][0], m2 = cb2[vec][0], m3 = cb3[vec][0];
      int j1 = ci1[vec][0], j2 = ci2[vec][0];
#pragma unroll
      for (int t = 1; t < 4; ++t) {
        ins3(cb1[vec][t], ci1[vec][t], m1, m2, m3, j1, j2);
        ins3(cb2[vec][t], ci2[vec][t], m1, m2, m3, j1, j2);
        ins3(cb3[vec][t], 0x7fffffff, m1, m2, m3, j1, j2);
      }
      int bi = j1;
      const size_t xoff = ibase + s0 + vec;
      if (m3 - m1 < TIE_T) {
        // 3-way near-tie: full exact scan (vanishingly rare)
        double bd = 1e300; int bj = 0;
        for (int e = 0; e < EDIM; ++e) {
          double a = score64(in, wt, xoff, e);
          if (a < bd) { bd = a; bj = e; }
        }
        bi = bj;
      } else if (m2 - m1 < TIE_T) {
        double s1 = score64(in, wt, xoff, j1);
        double s2 = score64(in, wt, xoff, j2);
        if (s2 < s1 || (s2 == s1 && j2 < j1)) bi = j2;
      }
      sIdx[vec] = bi;
      atomicAdd(&hist[bi], 1);
    }
  }
  __syncthreads();

  // ---- out_q + loss: x reconstructed from LDS hi/lo (no global re-read)
  {
    const int vec = tid & (MT - 1);
    const int qd  = tid >> 6;             // 4 quarters of 32 channels
    const int bi  = sIdx[vec];
    const float* wq = wt + (size_t)bi * CDIM;
    const size_t gbase = ibase + s0 + vec;
    const int fv = (vec & 15) ^ ((vec & 15) >> 2);
    double ls = 0.0;
#pragma unroll
    for (int cc = 0; cc < 32; cc += 4) {
      const int c = qd * 32 + cc;
      const int elem = (c >> 3) * 512 + (vec >> 4) * 128 + fv * 8 + (c & 7);
      uint2 hq = *(const uint2*)&xhi[elem];
      uint2 lq = *(const uint2*)&xlo[elem];
      float xs0 = __uint_as_float(hq.x << 16)        + __uint_as_float(lq.x << 16);
      float xs1 = __uint_as_float(hq.x & 0xffff0000u) + __uint_as_float(lq.x & 0xffff0000u);
      float xs2 = __uint_as_float(hq.y << 16)        + __uint_as_float(lq.y << 16);
      float xs3 = __uint_as_float(hq.y & 0xffff0000u) + __uint_as_float(lq.y & 0xffff0000u);
      float4 qv = *(const float4*)(wq + c);
      __builtin_nontemporal_store(qv.x, out_q + gbase + (size_t)(c + 0) * SPATIAL);
      __builtin_nontemporal_store(qv.y, out_q + gbase + (size_t)(c + 1) * SPATIAL);
      __builtin_nontemporal_store(qv.z, out_q + gbase + (size_t)(c + 2) * SPATIAL);
      __builtin_nontemporal_store(qv.w, out_q + gbase + (size_t)(c + 3) * SPATIAL);
      double d0 = (double)qv.x - (double)xs0; ls = fma(d0, d0, ls);
      double d1 = (double)qv.y - (double)xs1; ls = fma(d1, d1, ls);
      double d2 = (double)qv.z - (double)xs2; ls = fma(d2, d2, ls);
      double d3 = (double)qv.w - (double)xs3; ls = fma(d3, d3, ls);
    }
#pragma unroll
    for (int off = 32; off > 0; off >>= 1) ls += __shfl_down(ls, off);
    if (lane == 0) lredw[wv] = ls;
  }
  __syncthreads();
  if (tid == 0) atomicAdd(&ws->lossAcc, lredw[0] + lredw[1] + lredw[2] + lredw[3]);

  // ---- encodings: 64 one-hot rows, 256 u64 columns
  {
    const size_t r0 = (size_t)blockIdx.x * MT;
    const int c0 = tid * 2;
    unsigned long long* e2 = (unsigned long long*)enc;
    for (int r = 0; r < MT; ++r) {
      int idx = sIdx[r];
      union { float2 f; unsigned long long u; } cvt;
      cvt.f.x = (idx == c0) ? 1.0f : 0.0f;
      cvt.f.y = (idx == c0 + 1) ? 1.0f : 0.0f;
      __builtin_nontemporal_store(cvt.u, e2 + (r0 + (size_t)r) * (EDIM / 2) + tid);
    }
  }

  for (int e = tid; e < EDIM; e += BLK) {
    int v = hist[e];
    if (v) atomicAdd(&ws->counts[e], v);
  }
}

// ---- finalize
__global__ __launch_bounds__(512) void vq_fin(const WS* __restrict__ ws, float* __restrict__ out) {
  __shared__ double red[EDIM];
  int t = threadIdx.x;
  double p = (double)ws->counts[t] * (1.0 / (double)NVEC);
  red[t] = p * log(p + 1e-10);
  __syncthreads();
  for (int off = 256; off > 0; off >>= 1) {
    if (t < off) red[t] += red[t + off];
    __syncthreads();
  }
  if (t == 0) {
    out[0] = (float)(1.25 * ws->lossAcc / (double)QELEMS);
    out[1 + QELEMS] = (float)exp(-red[0]);
  }
}

extern "C" void kernel_launch(void* const* d_in, const int* in_sizes, int n_in,
                              void* d_out, int out_size, void* d_ws, size_t ws_size,
                              hipStream_t stream) {
  const float* in = (const float*)d_in[0];
  const float* wt = (const float*)d_in[1];
  float* out = (float*)d_out;
  WS* ws = (WS*)d_ws;

  float* out_q = out + 1;
  float* enc   = out + 2 + QELEMS;

  const bool useWP = (ws_size >= sizeof(WS));
  vq_pre<<<dim3(64), dim3(256), 0, stream>>>(wt, ws, useWP ? 1 : 0);
  if (useWP)
    vq_main<true><<<dim3(NVEC / MT), dim3(BLK), 0, stream>>>(in, wt, ws, out_q, enc);
  else
    vq_main<false><<<dim3(NVEC / MT), dim3(BLK), 0, stream>>>(in, wt, ws, out_q, enc);
  vq_fin<<<dim3(1), dim3(512), 0, stream>>>(ws, out);
}